// Round 10
// baseline (144.273 us; speedup 1.0000x reference)
//
#include <hip/hip_runtime.h>

typedef __bf16 bf16x8 __attribute__((ext_vector_type(8)));
typedef __bf16 bf16x2 __attribute__((ext_vector_type(2)));
typedef float  f32x4  __attribute__((ext_vector_type(4)));
typedef float  f32x16 __attribute__((ext_vector_type(16)));
typedef unsigned short u16;
typedef unsigned u32x2 __attribute__((ext_vector_type(2)));
typedef unsigned u32x4 __attribute__((ext_vector_type(4)));

// native RNE f32->bf16 (compiler emits v_cvt_pk_bf16_f32)
__device__ __forceinline__ u16 f2bf(float f) {
  return __builtin_bit_cast(u16, (__bf16)f);
}
// pack two f32 -> dword of 2 bf16 (lo = bits 0-15)
__device__ __forceinline__ unsigned pack2(float lo, float hi) {
  bf16x2 t;
  t[0] = (__bf16)lo; t[1] = (__bf16)hi;
  return __builtin_bit_cast(unsigned, t);
}

#define GLOAD16(g, l) __builtin_amdgcn_global_load_lds( \
    (__attribute__((address_space(1))) void*)(void*)(g), \
    (__attribute__((address_space(3))) void*)(l), 16, 0, 0)

// log2(e)/8 : folds softmax scale (1/sqrt(64)) and exp->exp2 conversion into Q
#define QSCALE 0.18033688011112042f

// ---------------------------------------------------------------- converts
// single segmented launch (boundaries block-uniform: 3072 / 864 / 288 blocks)
__global__ __launch_bounds__(256) void cvt_all(
    const float* __restrict__ x, const float* __restrict__ wq,
    const float* __restrict__ wp, unsigned* __restrict__ xb,
    unsigned* __restrict__ wqb, unsigned* __restrict__ wpb) {
  int i = blockIdx.x * 256 + threadIdx.x;
  const float* src;
  unsigned* dst;
  if (i < 786432) {                 // x: 6291456 f32 = 786432 vec8
    src = x; dst = xb;
  } else if (i < 786432 + 221184) { // Wqkv: 1769472 f32
    src = wq; dst = wqb; i -= 786432;
  } else {                          // Wproj: 589824 f32
    src = wp; dst = wpb; i -= 786432 + 221184;
  }
  const float4* s = (const float4*)src + 2 * (size_t)i;
  float4 a = s[0], b = s[1];
  u32x4 o = {pack2(a.x, a.y), pack2(a.z, a.w), pack2(b.x, b.y), pack2(b.z, b.w)};
  *((u32x4*)dst + i) = o;
}

// ---------------------------------------------------------------- GEMM (TN)
// C[m][n] = sum_k A[m][k]*B[n][k]; 128x128 tile, BK=32, double-buffered LDS,
// one barrier per K-step (stage(next) overlaps compute(cur)).
template<int EPI>
__global__ __launch_bounds__(256) void gemm_tn(
    const u16* __restrict__ A, const u16* __restrict__ B,
    const float* __restrict__ bias, float* __restrict__ outF,
    u16* __restrict__ qws, u16* __restrict__ kws, u16* __restrict__ vtws,
    int M, int N, int K) {
  __shared__ __align__(16) u16 As[8192];   // 2 x [128][32]
  __shared__ __align__(16) u16 Bs[8192];
  const int tid = threadIdx.x;
  const int ln = tid & 63, wv = tid >> 6;
  const int wr = wv >> 1, wc = wv & 1;
  const int m0 = blockIdx.x * 128, n0 = blockIdx.y * 128;

  f32x4 acc[4][4] = {};

  const int c0 = tid, c1 = tid + 256;
  const int r0 = c0 >> 2, kc0 = ((c0 & 3) ^ ((r0 >> 1) & 3)) * 8;
  const int r1 = c1 >> 2, kc1 = ((c1 & 3) ^ ((r1 >> 1) & 3)) * 8;
  const u16* ag0 = A + (size_t)(m0 + r0) * K + kc0;
  const u16* ag1 = A + (size_t)(m0 + r1) * K + kc1;
  const u16* bg0 = B + (size_t)(n0 + r0) * K + kc0;
  const u16* bg1 = B + (size_t)(n0 + r1) * K + kc1;

  // prologue: stage k0=0 into buffer 0
  GLOAD16(ag0, As + wv * 512);
  GLOAD16(ag1, As + 2048 + wv * 512);
  GLOAD16(bg0, Bs + wv * 512);
  GLOAD16(bg1, Bs + 2048 + wv * 512);
  __syncthreads();

  int cur = 0;
  for (int k0 = 0; k0 < K; k0 += 32) {
    const int nxt = cur ^ 1;
    if (k0 + 32 < K) {
      GLOAD16(ag0 + k0 + 32, As + nxt * 4096 + wv * 512);
      GLOAD16(ag1 + k0 + 32, As + nxt * 4096 + 2048 + wv * 512);
      GLOAD16(bg0 + k0 + 32, Bs + nxt * 4096 + wv * 512);
      GLOAD16(bg1 + k0 + 32, Bs + nxt * 4096 + 2048 + wv * 512);
    }
    const u16* ab = As + cur * 4096;
    const u16* bb = Bs + cur * 4096;
    bf16x8 af[4], bfr[4];
#pragma unroll
    for (int i = 0; i < 4; ++i) {
      int ra = wr * 64 + i * 16 + (ln & 15);
      af[i] = *(const bf16x8*)(ab + ra * 32 + (((ln >> 4) ^ ((ra >> 1) & 3)) * 8));
      int rb = wc * 64 + i * 16 + (ln & 15);
      bfr[i] = *(const bf16x8*)(bb + rb * 32 + (((ln >> 4) ^ ((rb >> 1) & 3)) * 8));
    }
#pragma unroll
    for (int i = 0; i < 4; ++i)
#pragma unroll
      for (int j = 0; j < 4; ++j)
        acc[i][j] = __builtin_amdgcn_mfma_f32_16x16x32_bf16(af[i], bfr[j], acc[i][j], 0, 0, 0);
    __syncthreads();
    cur = nxt;
  }

  if (EPI == 1) {
#pragma unroll
    for (int j = 0; j < 4; ++j) {
      int col = n0 + wc * 64 + j * 16 + (ln & 15);
      float bj = bias[col];
#pragma unroll
      for (int i = 0; i < 4; ++i) {
        int mr = m0 + wr * 64 + i * 16 + ((ln >> 4) << 2);
#pragma unroll
        for (int r = 0; r < 4; ++r)
          outF[(size_t)(mr + r) * N + col] = acc[i][j][r] + bj;
      }
    }
  } else {
    const int s = n0 / 768;  // 0=q 1=k 2=v (block-uniform; 768%128==0)
#pragma unroll
    for (int j = 0; j < 4; ++j) {
      int col = n0 + wc * 64 + j * 16 + (ln & 15);
      float bj = bias[col];
      int ns = col - s * 768;
      int h = ns >> 6, d = ns & 63;
      int dc = d >> 4, hid = (d >> 3) & 1, jd = d & 7;
#pragma unroll
      for (int i = 0; i < 4; ++i) {
        int m = m0 + wr * 64 + i * 16 + ((ln >> 4) << 2);
        int b = m >> 11, iseq = m & 2047;
        size_t bh = (size_t)(b * 12 + h);
        if (s == 0) {
#pragma unroll
          for (int r = 0; r < 4; ++r)
            qws[(bh * 2048 + iseq + r) * 64 + d] = f2bf((acc[i][j][r] + bj) * QSCALE);
        } else if (s == 1) {
          // K in attn A-FRAGMENT-READY layout:
          // [bh][tile=n>>5][dc=d>>4][lane=((d>>3)&1)*32 + pi(n&31)][j=d&7],
          // pi = swap bits 2<->3. attn lane ln then loads its QK A-fragment
          // as a fully-coalesced 1KB wave-read: tile*2048 + dc*512 + ln*8.
#pragma unroll
          for (int r = 0; r < 4; ++r) {
            int row = iseq + r, rr = row & 31;
            int pl = (rr & ~12) | ((rr & 4) << 1) | ((rr & 8) >> 1);
            kws[((size_t)bh * 64 + (row >> 5)) * 2048 + dc * 512 +
                (hid * 32 + pl) * 8 + jd] = f2bf(acc[i][j][r] + bj);
          }
        } else {
          // V^T tile-blocked: [bh][tile=k>>5][wc=(k>>3)&3][d][j=k&7] —
          // attn V fragments are coalesced 512B half-wave reads.
          u32x2 pk = {pack2(acc[i][j][0] + bj, acc[i][j][1] + bj),
                      pack2(acc[i][j][2] + bj, acc[i][j][3] + bj)};
          *(u32x2*)(vtws + ((size_t)bh * 64 + (iseq >> 5)) * 2048 +
                    ((iseq >> 3) & 3) * 512 + (size_t)d * 8 + (iseq & 7)) = pk;
        }
      }
    }
  }
}

// ---------------------------------------------------------------- flash attn
// R10: LDS-FREE, BARRIER-FREE loop. Diagnosis ladder: chain-bound QK->exp->PV
// with 12 waves/CU; every in-geometry lever null (R5 vmcnt, R9 stagger) or
// spilled (R6). The geometry was forced by LDS staging (occupancy + barriers)
// and the 170-reg cap. Both removed:
//   - K is read per-lane DIRECTLY from global in fragment-ready layout
//     (GEMM writes [bh][tile][dc][lane][8] with the pi-permutation baked into
//     the lane slot) -> each fragment load = coalesced 1KB wave-read.
//   - V read directly from the tile-blocked layout (512B half-wave reads).
//   - Loop has NO ds_read/ds_write/global_load_lds/__syncthreads. Operands
//     reload in place, issued one phase early (K after QK, V after PV) so
//     ~600cy of compute covers L1/L2 latency. Sharing now via L1/L2 (dense
//     reads, XCD working set 3MB < 4MB L2) — avoids R8's private-staging
//     duplication since there is no staging at all.
//   - Geometry: 32q x 4 p-split waves (each wave 32q x 512 KV, 16 iters);
//     grid (64,48)=3072 blocks = EXACTLY 3 rounds of 4 blocks/CU at
//     launch_bounds(256,4) (live set ~115 regs < 128) -> 16 waves/CU (+33%).
//   - LDS only for the epilogue (O,l) combine (R8's proven exchange).
// Math unchanged: swapped-operand 32x32x16 S^T = mfma(K,Q^T); exp2
// shift-invariant softmax (no max); VALU denominator; in-lane P pack via pi.
__global__ __launch_bounds__(256, 4) void attn_fa(
    const u16* __restrict__ qws, const u16* __restrict__ kfws,
    const u16* __restrict__ vtws, u16* __restrict__ aows) {
  __shared__ float EX[6528];   // 3 exporting waves x 2112 + 3x64 lg
  const int tid = threadIdx.x, ln = tid & 63, wv = tid >> 6;
  const int lq = ln & 31, hi = ln >> 5;

  // XCD-chunked swizzle: 6 bh per XCD -> K+V working set L2-resident
  const int flat = blockIdx.y * 64 + blockIdx.x;   // grid (64,48)
  const int xcd = flat & 7, jj = flat >> 3;        // jj 0..383
  const int bh = xcd * 6 + (jj % 6);
  const int q0 = (jj / 6) * 32;                    // 64 q-tiles of 32

  const int kv0 = wv * 512;                        // wave's KV quarter
  const size_t kbase = (size_t)bh * 2048 * 64;     // qws: [bh][n][64]

  // Q^T B-fragments (col=q=lq, k-rows = dc*16 + hi*8 + 0..7)
  bf16x8 qf[4];
  {
    const u16* qp = qws + kbase + (size_t)(q0 + lq) * 64 + hi * 8;
#pragma unroll
    for (int dc = 0; dc < 4; ++dc) qf[dc] = *(const bf16x8*)(qp + dc * 16);
  }

  const f32x16 zc = {};
  f32x16 o0 = {}, o1 = {};   // O^T: d rows 0..31 / 32..63, col q=lq
  float lsum = 0.f;

  // fragment bases (both layouts tile-major, 2048 u16 per tile)
  const u16* kfb = kfws + ((size_t)bh * 64 + (kv0 >> 5)) * 2048 + ln * 8;
  const u16* vfb = vtws + ((size_t)bh * 64 + (kv0 >> 5)) * 2048;
  const int vA0 = hi * 512 + lq * 8;   // c=0, d=lq
  const int vB0 = vA0 + 256;           // c=0, d=32+lq
  const int vA1 = vA0 + 1024;          // c=1, d=lq
  const int vB1 = vA1 + 256;           // c=1, d=32+lq

  bf16x8 kf0, kf1, kf2, kf3, va0, vb0, va1, vb1;

#define LOADK(t) do { const u16* kp_ = kfb + (size_t)(t) * 2048; \
    kf0 = *(const bf16x8*)(kp_);        kf1 = *(const bf16x8*)(kp_ + 512); \
    kf2 = *(const bf16x8*)(kp_ + 1024); kf3 = *(const bf16x8*)(kp_ + 1536); \
  } while (0)
#define LOADV(t) do { const u16* vp_ = vfb + (size_t)(t) * 2048; \
    va0 = *(const bf16x8*)(vp_ + vA0); vb0 = *(const bf16x8*)(vp_ + vB0); \
    va1 = *(const bf16x8*)(vp_ + vA1); vb1 = *(const bf16x8*)(vp_ + vB1); \
  } while (0)

  LOADK(0);
  LOADV(0);
  for (int t = 0; t < 16; ++t) {
    // QK: S^T = sum_dc mfma(K-frag, Q-frag)
    f32x16 s = __builtin_amdgcn_mfma_f32_32x32x16_bf16(kf0, qf[0], zc, 0, 0, 0);
    s = __builtin_amdgcn_mfma_f32_32x32x16_bf16(kf1, qf[1], s, 0, 0, 0);
    s = __builtin_amdgcn_mfma_f32_32x32x16_bf16(kf2, qf[2], s, 0, 0, 0);
    s = __builtin_amdgcn_mfma_f32_32x32x16_bf16(kf3, qf[3], s, 0, 0, 0);
    // K(t+1) reload in place: covered by exp+PV below (~600cy)
    if (t + 1 < 16) LOADK(t + 1);

    // P = exp2(S) (shift-invariant softmax); denominator on VALU (2 accums)
    float a = 0.f, b2 = 0.f;
#pragma unroll
    for (int r = 0; r < 16; r += 2) {
      float e0 = __builtin_amdgcn_exp2f(s[r]);     s[r] = e0;     a  += e0;
      float e1 = __builtin_amdgcn_exp2f(s[r + 1]); s[r + 1] = e1; b2 += e1;
    }
    lsum += a + b2;
    // in-lane pack (pi-permuted K rows): chunk c = regs [c*8..c*8+7]
    u32x4 P0 = {pack2(s[0], s[1]),   pack2(s[2], s[3]),
                pack2(s[4], s[5]),   pack2(s[6], s[7])};
    u32x4 P1 = {pack2(s[8], s[9]),   pack2(s[10], s[11]),
                pack2(s[12], s[13]), pack2(s[14], s[15])};
    bf16x8 p0 = __builtin_bit_cast(bf16x8, P0);
    bf16x8 p1 = __builtin_bit_cast(bf16x8, P1);

    // PV
    o0 = __builtin_amdgcn_mfma_f32_32x32x16_bf16(va0, p0, o0, 0, 0, 0);
    o1 = __builtin_amdgcn_mfma_f32_32x32x16_bf16(vb0, p0, o1, 0, 0, 0);
    o0 = __builtin_amdgcn_mfma_f32_32x32x16_bf16(va1, p1, o0, 0, 0, 0);
    o1 = __builtin_amdgcn_mfma_f32_32x32x16_bf16(vb1, p1, o1, 0, 0, 0);
    // V(t+1) reload in place: covered by QK+exp of t+1
    if (t + 1 < 16) LOADV(t + 1);
  }
#undef LOADV
#undef LOADK

  // quarter denominator: lane holds 16 of each tile's 32 k-rows; lane^32
  // holds the rest (same q=lq)
  float lg = lsum + __shfl_xor(lsum, 32);

  // combine the 4 KV quarters (plain addition): waves 1-3 export, wave 0
  // adds + stores. Lane-major [r][ln] layout: conflict-free.
  if (wv > 0) {
    float* w = EX + (wv - 1) * 2112 + ln;
#pragma unroll
    for (int r = 0; r < 16; ++r) {
      w[r * 64]        = o0[r];
      w[(16 + r) * 64] = o1[r];
    }
    EX[6336 + (wv - 1) * 64 + ln] = lg;
  }
  __syncthreads();
  if (wv == 0) {
#pragma unroll
    for (int w2 = 0; w2 < 3; ++w2) {
      const float* w = EX + w2 * 2112 + ln;
#pragma unroll
      for (int r = 0; r < 16; ++r) {
        o0[r] += w[r * 64];
        o1[r] += w[(16 + r) * 64];
      }
      lg += EX[6336 + w2 * 64 + ln];
    }
    const float rl = 1.0f / lg;
    const int b = bh / 12, h = bh % 12;
    u16* orow = aows + (size_t)(b * 2048 + q0 + lq) * 768 + h * 64;
#pragma unroll
    for (int t2 = 0; t2 < 4; ++t2) {
      u32x2 pk0 = {pack2(o0[4 * t2 + 0] * rl, o0[4 * t2 + 1] * rl),
                   pack2(o0[4 * t2 + 2] * rl, o0[4 * t2 + 3] * rl)};
      u32x2 pk1 = {pack2(o1[4 * t2 + 0] * rl, o1[4 * t2 + 1] * rl),
                   pack2(o1[4 * t2 + 2] * rl, o1[4 * t2 + 3] * rl)};
      *(u32x2*)(orow + t2 * 8 + 4 * hi)      = pk0;   // d = 8t2+4hi+r
      *(u32x2*)(orow + 32 + t2 * 8 + 4 * hi) = pk1;   // d = 32+8t2+4hi+r
    }
  }
}

// ---------------------------------------------------------------- launch
extern "C" void kernel_launch(void* const* d_in, const int* in_sizes, int n_in,
                              void* d_out, int out_size, void* d_ws, size_t ws_size,
                              hipStream_t stream) {
  const float* x     = (const float*)d_in[0];
  const float* Wqkv  = (const float*)d_in[1];
  const float* bqkv  = (const float*)d_in[2];
  const float* Wproj = (const float*)d_in[3];
  const float* bproj = (const float*)d_in[4];
  float* out = (float*)d_out;

  u16* xb   = (u16*)d_ws;          // 6291456
  u16* wqb  = xb  + 6291456;       // 1769472
  u16* wpb  = wqb + 1769472;       // 589824
  u16* qws  = wpb + 589824;        // 6291456  [bh][n][64], pre-scaled QSCALE
  u16* kws  = qws + 6291456;       // 6291456  [bh][64tile][4dc][64lane][8] frag-ready K
  u16* vtws = kws + 6291456;       // 6291456  [bh][32tile][4wc][64d][8] tile-blocked V^T
  u16* aows = vtws + 6291456;      // 6291456  [b*2048+q][768]

  cvt_all<<<4224, 256, 0, stream>>>(x, Wqkv, Wproj,
                                    (unsigned*)xb, (unsigned*)wqb, (unsigned*)wpb);

  gemm_tn<0><<<dim3(64, 18), 256, 0, stream>>>(xb, wqb, bqkv, nullptr,
                                               qws, kws, vtws, 8192, 2304, 768);
  attn_fa<<<dim3(64, 48), 256, 0, stream>>>(qws, kws, vtws, aows);
  gemm_tn<1><<<dim3(64, 6), 256, 0, stream>>>(aows, wpb, bproj, out,
                                              nullptr, nullptr, nullptr,
                                              8192, 768, 768);
}